// Round 10
// baseline (127.153 us; speedup 1.0000x reference)
//
#include <hip/hip_runtime.h>

#define B_ 8
#define T_ 1024
#define C_ 768
#define H_ 12
#define D_ 64
#define M_ (B_*T_)      // 8192 rows
#define N3_ (3*C_)      // 2304
#define NQK_ 1536       // Q|K packed row stride

// Q pre-scale: 1/sqrt(64) * log2(e)  (softmax runs in exp2 domain)
#define QSCALE 0.18033688011112042f

typedef __bf16 bf16x8 __attribute__((ext_vector_type(8)));
typedef float f32x4 __attribute__((ext_vector_type(4)));

__device__ __forceinline__ ushort f2bf(float f){
  __bf16 h = (__bf16)f;                 // RNE; compiler emits v_cvt_pk_bf16_f32
  return __builtin_bit_cast(ushort, h);
}

// async global->LDS, 16B per lane; LDS dest = wave-uniform base + lane*16
__device__ __forceinline__ void gload_lds16(const void* g, void* l){
  __builtin_amdgcn_global_load_lds(
      (const __attribute__((address_space(1))) void*)g,
      (__attribute__((address_space(3))) void*)l, 16, 0, 0);
}

// ---- fp32 -> bf16 elementwise (n % 4 == 0) ----
__global__ void cvt_f32_bf16(const float* __restrict__ in, ushort* __restrict__ out, int n){
  int i = (blockIdx.x * blockDim.x + threadIdx.x) * 4;
  if (i >= n) return;
  float4 f = *(const float4*)(in + i);
  ushort4 o = { f2bf(f.x), f2bf(f.y), f2bf(f.z), f2bf(f.w) };
  *(ushort4*)(out + i) = o;
}

// ---- fp32 [R][Cc] -> bf16 transposed [Cc][R] ----
__global__ void tconv(const float* __restrict__ in, ushort* __restrict__ out, int R, int Cc){
  __shared__ float tile[32][33];
  int c0 = blockIdx.x * 32, r0 = blockIdx.y * 32;
  for (int i = threadIdx.y; i < 32; i += 8)
    tile[i][threadIdx.x] = in[(size_t)(r0 + i) * Cc + c0 + threadIdx.x];
  __syncthreads();
  for (int i = threadIdx.y; i < 32; i += 8)
    out[(size_t)(c0 + i) * R + r0 + threadIdx.x] = f2bf(tile[threadIdx.x][i]);
}

// ---- 128x128x64 bf16 MFMA GEMM, DOUBLE-BUFFERED global_load_lds staging
// (T3-minimal counted-vmcnt pipeline): stage tile t+1 at iteration top,
// compute tile t, then vmcnt(0) + ONE raw s_barrier at iteration end --
// staging latency overlaps the whole MFMA phase. LDS 64KB is free:
// occupancy is VGPR-bound (80 VGPR + 64 AGPR acc ~ 2 blocks/CU), not LDS.
// Both-sides XOR swizzle (rule #21); bijective XCD-chunk swizzle.
// MODE 0: QKV -> qk[t][1536] (Q scaled) + Vt[bh][d][t] via LDS-bounce stores.
// MODE 1: f32 out + bias (projection), direct stores.
template<int MODE>
__global__ __launch_bounds__(256) void gemm_bt(const ushort* __restrict__ A, const ushort* __restrict__ BT,
                        const float* __restrict__ bias, float* __restrict__ Cf32,
                        ushort* __restrict__ qk, ushort* __restrict__ Vt,
                        int M, int N, int K){
  __shared__ __align__(16) ushort smem[32768];   // buf0: As|Bs, buf1: As|Bs (16KB each); Ts aliases
  const int tid = threadIdx.x;
  const int lane = tid & 63, w = tid >> 6;
  const int wr = w >> 1, wc = w & 1;
  const int lr = lane & 15, lg = lane >> 4;
  // XCD-chunk swizzle: each XCD gets a contiguous chunk of tile-ids.
  const int gdx = gridDim.x;
  const int total = gdx * gridDim.y;
  int id = blockIdx.y * gdx + blockIdx.x;
  int nid = (id & 7) * (total >> 3) + (id >> 3);
  const int m0 = (nid / gdx) * 128, n0 = (nid % gdx) * 128;
  f32x4 acc[4][4] = {};
  const int srow = lane >> 3;              // 0..7 within 8-row chunk
  const int sseg = (lane & 7) ^ srow;      // pre-swizzled source slot
  #define STAGE(bf, k0s)                                                       \
    _Pragma("unroll")                                                          \
    for (int c = 0; c < 4; ++c){                                               \
      int row = w*32 + c*8 + srow;                                             \
      gload_lds16(&A [(size_t)(m0 + row) * K + (k0s) + sseg * 8],              \
                  &smem[(bf)*16384 + (w*32 + c*8) * 64]);                      \
      gload_lds16(&BT[(size_t)(n0 + row) * K + (k0s) + sseg * 8],              \
                  &smem[(bf)*16384 + 8192 + (w*32 + c*8) * 64]);               \
    }
  // prologue: stage tile 0, drain, sync
  STAGE(0, 0)
  asm volatile("s_waitcnt vmcnt(0)" ::: "memory");
  __builtin_amdgcn_sched_barrier(0);
  __builtin_amdgcn_s_barrier();
  __builtin_amdgcn_sched_barrier(0);
  int cur = 0;
  for (int k0 = 0; k0 < K; k0 += 64){
    if (k0 + 64 < K) { STAGE(cur ^ 1, k0 + 64) }   // issue next tile's loads
    __builtin_amdgcn_sched_barrier(0);             // keep issue above compute
    const ushort* Asb = &smem[cur * 16384];
    const ushort* Bsb = &smem[cur * 16384 + 8192];
    #pragma unroll
    for (int kk = 0; kk < 64; kk += 32){
      bf16x8 af[4], bfr[4];
      #pragma unroll
      for (int m = 0; m < 4; ++m)
        af[m]  = *(const bf16x8*)&Asb[(wr*64 + m*16 + lr) * 64 + ((kk + lg*8) ^ ((lr & 7) << 3))];
      #pragma unroll
      for (int n = 0; n < 4; ++n)
        bfr[n] = *(const bf16x8*)&Bsb[(wc*64 + n*16 + lr) * 64 + ((kk + lg*8) ^ ((lr & 7) << 3))];
      #pragma unroll
      for (int m = 0; m < 4; ++m)
        #pragma unroll
        for (int n = 0; n < 4; ++n)
          acc[m][n] = __builtin_amdgcn_mfma_f32_16x16x32_bf16(af[m], bfr[n], acc[m][n], 0, 0, 0);
    }
    // end of tile: next-tile loads (issued at top) had the whole compute to land
    __builtin_amdgcn_sched_barrier(0);
    asm volatile("s_waitcnt vmcnt(0)" ::: "memory");
    __builtin_amdgcn_sched_barrier(0);
    __builtin_amdgcn_s_barrier();                  // all writes visible, all reads done
    __builtin_amdgcn_sched_barrier(0);
    cur ^= 1;
  }
  #undef STAGE
  // C/D layout: row = 4*(lane>>4)+i, col = lane&15  [measured m89]
  if (MODE == 1){
    #pragma unroll
    for (int n = 0; n < 4; ++n){
      int col = n0 + wc*64 + n*16 + lr;
      float bv = bias[col];
      #pragma unroll
      for (int m = 0; m < 4; ++m){
        int rowb = m0 + wr*64 + m*16 + lg*4;
        #pragma unroll
        for (int i = 0; i < 4; ++i)
          Cf32[(size_t)(rowb + i) * N + col] = acc[m][n][i] + bv;
      }
    }
  } else {
    constexpr int LDC = 136;         // rows 272B: 16B-aligned (~2-way banks)
    ushort* Ts = smem;               // 128*136 = 17408 ushorts (aliases bufs; loop barrier protects)
    const bool isV = (n0 >= 2*C_);
    #pragma unroll
    for (int n = 0; n < 4; ++n){
      int cl = wc*64 + n*16 + lr;
      int col = n0 + cl;
      float bv = bias[col];
      float sc = (col < C_) ? QSCALE : 1.0f;
      if (isV){
        int rl = wr*64;
        #pragma unroll
        for (int m = 0; m < 4; ++m){
          ushort4 o;
          #pragma unroll
          for (int i = 0; i < 4; ++i) ((ushort*)&o)[i] = f2bf(acc[m][n][i] + bv);
          *(ushort4*)&Ts[cl * LDC + rl + m*16 + lg*4] = o;     // transposed: Ts[c][r]
        }
      } else {
        #pragma unroll
        for (int m = 0; m < 4; ++m){
          int rl = wr*64 + m*16 + lg*4;
          #pragma unroll
          for (int i = 0; i < 4; ++i)
            Ts[(rl + i) * LDC + cl] = f2bf((acc[m][n][i] + bv) * sc);  // Ts[r][c]
        }
      }
    }
    __syncthreads();
    const int bb = m0 >> 10, tt = m0 & 1023;
    #pragma unroll
    for (int it = 0; it < 8; ++it){
      int idx = tid + it * 256;
      int rc = idx >> 4, sg = idx & 15;
      int4 v = *(const int4*)&Ts[rc * LDC + sg * 8];
      if (isV){
        int ch = n0 - 2*C_ + rc;               // 0..767
        int hh = ch >> 6, dd = ch & 63;
        *(int4*)&Vt[((size_t)(bb * H_ + hh) * 64 + dd) * 1024 + tt + sg * 8] = v;
      } else {
        *(int4*)&qk[(size_t)(m0 + rc) * NQK_ + n0 + sg * 8] = v;
      }
    }
  }
}

// ---- fused causal flash attention: 1 wave/block, DOUBLE-BUFFERED private
// LDS staging with counted vmcnt (no barriers at all -- wave-private LDS).
// Per k-tile: issue next tile's 16 gload_lds into buf^1, then vmcnt(16)
// (current tile's loads done, next stays in flight across compute).
// S^T = K*Q^T; unstabilized exp2 softmax; Y^T = V^T*P^T via per-block Ps.
__global__ __launch_bounds__(64, 4) void attn_fused(const ushort* __restrict__ qk,
                        const ushort* __restrict__ Vt, ushort* __restrict__ ya){
  constexpr int LD = 72;
  __shared__ __align__(16) ushort KVs[2 * 8192];  // buf: K[64*64] | V[64*64]; 32KB
  __shared__ __align__(16) ushort Ps[32 * LD];    // 4.6KB
  const int lane = threadIdx.x & 63;
  const int lr = lane & 15, lg = lane >> 4;
  const int srow = lane >> 3;              // 0..7: row within 8-row chunk
  const int sseg = (lane & 7) ^ srow;      // pre-swizzled source slot
  // bx -> (xcd, head-in-xcd, q-slice); heavy q-slices first within each XCD.
  const int bx = blockIdx.x;
  const int xcd = bx & 7, ii = bx >> 3;    // ii in 0..383
  const int hi = ii % 12, qwi = ii / 12;   // qwi in 0..31
  const int qw = 31 - qwi;                 // heavy first
  const int bh = xcd * 12 + hi;
  const int b = bh / H_, h = bh % H_;
  const ushort* Kb = qk + (size_t)b * T_ * NQK_ + C_ + h * D_;   // row stride NQK_
  const ushort* Vb = Vt + (size_t)bh * D_ * T_;                  // [d][t]

  // Q frags in registers (already scaled by QSCALE in gemm1 epilogue)
  bf16x8 qf[2][2];
  #pragma unroll
  for (int n = 0; n < 2; ++n){
    int qr = qw*32 + n*16 + lr;
    const ushort* qp = qk + ((size_t)(b * T_ + qr)) * NQK_ + h * D_;
    #pragma unroll
    for (int kk = 0; kk < 2; ++kk)
      qf[n][kk] = __builtin_bit_cast(bf16x8, *(const int4*)(qp + kk*32 + lg*8));
  }

  #define STAGEKV(bf, kt)                                                      \
    _Pragma("unroll")                                                          \
    for (int c = 0; c < 8; ++c)                                                \
      gload_lds16(&Kb[(size_t)((kt)*64 + c*8 + srow) * NQK_ + sseg * 8],       \
                  &KVs[(bf)*8192 + c * 512]);                                  \
    _Pragma("unroll")                                                          \
    for (int c = 0; c < 8; ++c)                                                \
      gload_lds16(&Vb[(size_t)(c*8 + srow) * T_ + (kt)*64 + sseg * 8],         \
                  &KVs[(bf)*8192 + 4096 + c * 512]);

  f32x4 yacc[4][2] = {};
  float lsum[2] = {0.f, 0.f};             // per-lane partial row-sums
  const int qwmin = qw*32;
  const int nktw = ((qwmin + 31) >> 6) + 1;
  int cur = 0;
  STAGEKV(0, 0)                           // prologue: tile 0 in flight
  for (int kt = 0; kt < nktw; ++kt){
    if (kt + 1 < nktw){
      STAGEKV(cur ^ 1, kt + 1)            // issue next tile (16 loads)
      asm volatile("s_waitcnt vmcnt(16)" ::: "memory");  // current tile done
    } else {
      asm volatile("s_waitcnt vmcnt(0)" ::: "memory");
    }
    __builtin_amdgcn_sched_barrier(0);
    const ushort* Ksb = &KVs[cur * 8192];
    const ushort* Vsb = &KVs[cur * 8192 + 4096];

    // ---- S^T[key][q] = K * Q^T (frags from swizzled LDS) ----
    f32x4 st[4][2] = {};
    #pragma unroll
    for (int kk = 0; kk < 2; ++kk){
      bf16x8 kf[4];
      #pragma unroll
      for (int m = 0; m < 4; ++m)
        kf[m] = *(const bf16x8*)&Ksb[(m*16 + lr) * 64 + ((kk*32 + lg*8) ^ ((lr & 7) << 3))];
      __builtin_amdgcn_s_setprio(1);
      #pragma unroll
      for (int m = 0; m < 4; ++m)
        #pragma unroll
        for (int n = 0; n < 2; ++n)
          st[m][n] = __builtin_amdgcn_mfma_f32_16x16x32_bf16(kf[m], qf[n][kk], st[m][n], 0, 0, 0);
      __builtin_amdgcn_s_setprio(0);
    }

    // ---- p = exp2(s) (mask only on diagonal tiles); per-lane lsum ----
    const bool needmask = (kt*64 + 63 > qwmin);
    #pragma unroll
    for (int n = 0; n < 2; ++n){
      int q = qwmin + n*16 + lr;
      float ps = 0.f;
      #pragma unroll
      for (int m = 0; m < 4; ++m){
        ushort4 pk;
        #pragma unroll
        for (int i = 0; i < 4; ++i){
          float s = st[m][n][i];
          if (needmask){
            int key = kt*64 + m*16 + lg*4 + i;
            s = (key <= q) ? s : -1e30f;
          }
          float p = __builtin_amdgcn_exp2f(s);
          ps += p;
          ((ushort*)&pk)[i] = f2bf(p);
        }
        *(ushort4*)&Ps[(n*16 + lr) * LD + m*16 + lg*4] = pk;
      }
      lsum[n] += ps;
    }

    // ---- PV: Y^T += V^T * P^T (V frags from swizzled LDS, P from Ps) ----
    #pragma unroll
    for (int kk = 0; kk < 2; ++kk){
      bf16x8 vf[4], pf[2];
      #pragma unroll
      for (int m = 0; m < 4; ++m)
        vf[m] = *(const bf16x8*)&Vsb[(m*16 + lr) * 64 + ((kk*32 + lg*8) ^ ((lr & 7) << 3))];
      #pragma unroll
      for (int n = 0; n < 2; ++n)
        pf[n] = *(const bf16x8*)&Ps[(n*16 + lr) * LD + kk*32 + lg*8];
      __builtin_amdgcn_s_setprio(1);
      #pragma unroll
      for (int m = 0; m < 4; ++m)
        #pragma unroll
        for (int n = 0; n < 2; ++n)
          yacc[m][n] = __builtin_amdgcn_mfma_f32_16x16x32_bf16(vf[m], pf[n], yacc[m][n], 0, 0, 0);
      __builtin_amdgcn_s_setprio(0);
    }
    cur ^= 1;
  }
  #undef STAGEKV
  // reduce lsum across the 4 lane-groups (once, after the loop)
  #pragma unroll
  for (int n = 0; n < 2; ++n){
    lsum[n] += __shfl_xor(lsum[n], 16);
    lsum[n] += __shfl_xor(lsum[n], 32);
  }
  // write ya[b, q, h*64 + d]; lane holds d = m*16 + lg*4 + i
  #pragma unroll
  for (int n = 0; n < 2; ++n){
    int q = qw*32 + n*16 + lr;
    float inv = 1.0f / lsum[n];
    #pragma unroll
    for (int m = 0; m < 4; ++m){
      ushort4 o;
      #pragma unroll
      for (int i = 0; i < 4; ++i) ((ushort*)&o)[i] = f2bf(yacc[m][n][i] * inv);
      *(ushort4*)&ya[(size_t)(b * T_ + q) * C_ + h * D_ + m*16 + lg*4] = o;
    }
  }
}

extern "C" void kernel_launch(void* const* d_in, const int* in_sizes, int n_in,
                              void* d_out, int out_size, void* d_ws, size_t ws_size,
                              hipStream_t stream){
  (void)in_sizes; (void)n_in; (void)out_size; (void)ws_size;
  const float* x  = (const float*)d_in[0];
  const float* Wa = (const float*)d_in[1];
  const float* ba = (const float*)d_in[2];
  const float* Wp = (const float*)d_in[3];
  const float* bp = (const float*)d_in[4];
  char* ws = (char*)d_ws;
  ushort* xb  = (ushort*)(ws);               // [8192][768] bf16 x (reused as ya)
  ushort* WaT = (ushort*)(ws + 12582912);    // [2304][768]
  ushort* WpT = (ushort*)(ws + 16121856);    // [768][768]
  ushort* qkb = (ushort*)(ws + 17301504);    // [8192][1536] Q(scaled)|K
  ushort* Vt  = (ushort*)(ws + 42467328);    // [96][64][1024]
  ushort* ya  = xb;                          // total 55,050,240 B

  cvt_f32_bf16<<<dim3((M_*C_)/1024), dim3(256), 0, stream>>>(x, xb, M_*C_);
  tconv<<<dim3(N3_/32, C_/32), dim3(32,8), 0, stream>>>(Wa, WaT, C_, N3_);
  tconv<<<dim3(C_/32, C_/32), dim3(32,8), 0, stream>>>(Wp, WpT, C_, C_);
  gemm_bt<0><<<dim3(N3_/128, M_/128), dim3(256), 0, stream>>>(xb, WaT, ba, nullptr, qkb, Vt, M_, N3_, C_);
  attn_fused<<<dim3(96*32), dim3(64), 0, stream>>>(qkb, Vt, ya);
  gemm_bt<1><<<dim3(C_/128, M_/128), dim3(256), 0, stream>>>(ya, WpT, bp, (float*)d_out, nullptr, nullptr, M_, C_, C_);
}

// Round 11
// 116.677 us; speedup vs baseline: 1.0898x; 1.0898x over previous
//
#include <hip/hip_runtime.h>

#define B_ 8
#define T_ 1024
#define C_ 768
#define H_ 12
#define D_ 64
#define M_ (B_*T_)      // 8192 rows
#define N3_ (3*C_)      // 2304
#define NQK_ 1536       // Q|K packed row stride

// Q pre-scale: 1/sqrt(64) * log2(e)  (softmax runs in exp2 domain)
#define QSCALE 0.18033688011112042f

typedef __bf16 bf16x8 __attribute__((ext_vector_type(8)));
typedef float f32x4 __attribute__((ext_vector_type(4)));

__device__ __forceinline__ ushort f2bf(float f){
  __bf16 h = (__bf16)f;                 // RNE; compiler emits v_cvt_pk_bf16_f32
  return __builtin_bit_cast(ushort, h);
}

// async global->LDS, 16B per lane; LDS dest = wave-uniform base + lane*16
__device__ __forceinline__ void gload_lds16(const void* g, void* l){
  __builtin_amdgcn_global_load_lds(
      (const __attribute__((address_space(1))) void*)g,
      (__attribute__((address_space(3))) void*)l, 16, 0, 0);
}

// ---- fp32 -> bf16 elementwise (n % 4 == 0) ----
__global__ void cvt_f32_bf16(const float* __restrict__ in, ushort* __restrict__ out, int n){
  int i = (blockIdx.x * blockDim.x + threadIdx.x) * 4;
  if (i >= n) return;
  float4 f = *(const float4*)(in + i);
  ushort4 o = { f2bf(f.x), f2bf(f.y), f2bf(f.z), f2bf(f.w) };
  *(ushort4*)(out + i) = o;
}

// ---- fp32 [R][Cc] -> bf16 transposed [Cc][R] ----
__global__ void tconv(const float* __restrict__ in, ushort* __restrict__ out, int R, int Cc){
  __shared__ float tile[32][33];
  int c0 = blockIdx.x * 32, r0 = blockIdx.y * 32;
  for (int i = threadIdx.y; i < 32; i += 8)
    tile[i][threadIdx.x] = in[(size_t)(r0 + i) * Cc + c0 + threadIdx.x];
  __syncthreads();
  for (int i = threadIdx.y; i < 32; i += 8)
    out[(size_t)(c0 + i) * R + r0 + threadIdx.x] = f2bf(tile[threadIdx.x][i]);
}

// ---- 128x128x64 bf16 MFMA GEMM, DOUBLE-BUFFERED global_load_lds staging
// (kept from round 10 -- it helped: stage t+1 at top, compute t, vmcnt(0)+
// one raw s_barrier at end; staging latency overlaps the MFMA phase; LDS
// 64KB is free since occupancy is VGPR-bound at 2 blocks/CU).
// Both-sides XOR swizzle (rule #21); bijective XCD-chunk swizzle.
// MODE 0: QKV -> qk[t][1536] (Q scaled) + Vt[bh][d][t] via LDS-bounce stores.
// MODE 1: f32 out + bias (projection), direct stores.
template<int MODE>
__global__ __launch_bounds__(256) void gemm_bt(const ushort* __restrict__ A, const ushort* __restrict__ BT,
                        const float* __restrict__ bias, float* __restrict__ Cf32,
                        ushort* __restrict__ qk, ushort* __restrict__ Vt,
                        int M, int N, int K){
  __shared__ __align__(16) ushort smem[32768];   // buf0: As|Bs, buf1: As|Bs; Ts aliases
  const int tid = threadIdx.x;
  const int lane = tid & 63, w = tid >> 6;
  const int wr = w >> 1, wc = w & 1;
  const int lr = lane & 15, lg = lane >> 4;
  // XCD-chunk swizzle: each XCD gets a contiguous chunk of tile-ids.
  const int gdx = gridDim.x;
  const int total = gdx * gridDim.y;
  int id = blockIdx.y * gdx + blockIdx.x;
  int nid = (id & 7) * (total >> 3) + (id >> 3);
  const int m0 = (nid / gdx) * 128, n0 = (nid % gdx) * 128;
  f32x4 acc[4][4] = {};
  const int srow = lane >> 3;              // 0..7 within 8-row chunk
  const int sseg = (lane & 7) ^ srow;      // pre-swizzled source slot
  #define STAGE(bf, k0s)                                                       \
    _Pragma("unroll")                                                          \
    for (int c = 0; c < 4; ++c){                                               \
      int row = w*32 + c*8 + srow;                                             \
      gload_lds16(&A [(size_t)(m0 + row) * K + (k0s) + sseg * 8],              \
                  &smem[(bf)*16384 + (w*32 + c*8) * 64]);                      \
      gload_lds16(&BT[(size_t)(n0 + row) * K + (k0s) + sseg * 8],              \
                  &smem[(bf)*16384 + 8192 + (w*32 + c*8) * 64]);               \
    }
  // prologue: stage tile 0, drain, sync
  STAGE(0, 0)
  asm volatile("s_waitcnt vmcnt(0)" ::: "memory");
  __builtin_amdgcn_sched_barrier(0);
  __builtin_amdgcn_s_barrier();
  __builtin_amdgcn_sched_barrier(0);
  int cur = 0;
  for (int k0 = 0; k0 < K; k0 += 64){
    if (k0 + 64 < K) { STAGE(cur ^ 1, k0 + 64) }   // issue next tile's loads
    __builtin_amdgcn_sched_barrier(0);             // keep issue above compute
    const ushort* Asb = &smem[cur * 16384];
    const ushort* Bsb = &smem[cur * 16384 + 8192];
    #pragma unroll
    for (int kk = 0; kk < 64; kk += 32){
      bf16x8 af[4], bfr[4];
      #pragma unroll
      for (int m = 0; m < 4; ++m)
        af[m]  = *(const bf16x8*)&Asb[(wr*64 + m*16 + lr) * 64 + ((kk + lg*8) ^ ((lr & 7) << 3))];
      #pragma unroll
      for (int n = 0; n < 4; ++n)
        bfr[n] = *(const bf16x8*)&Bsb[(wc*64 + n*16 + lr) * 64 + ((kk + lg*8) ^ ((lr & 7) << 3))];
      #pragma unroll
      for (int m = 0; m < 4; ++m)
        #pragma unroll
        for (int n = 0; n < 4; ++n)
          acc[m][n] = __builtin_amdgcn_mfma_f32_16x16x32_bf16(af[m], bfr[n], acc[m][n], 0, 0, 0);
    }
    // end of tile: next-tile loads (issued at top) had the whole compute to land
    __builtin_amdgcn_sched_barrier(0);
    asm volatile("s_waitcnt vmcnt(0)" ::: "memory");
    __builtin_amdgcn_sched_barrier(0);
    __builtin_amdgcn_s_barrier();                  // all writes visible, all reads done
    __builtin_amdgcn_sched_barrier(0);
    cur ^= 1;
  }
  #undef STAGE
  // C/D layout: row = 4*(lane>>4)+i, col = lane&15  [measured m89]
  if (MODE == 1){
    #pragma unroll
    for (int n = 0; n < 4; ++n){
      int col = n0 + wc*64 + n*16 + lr;
      float bv = bias[col];
      #pragma unroll
      for (int m = 0; m < 4; ++m){
        int rowb = m0 + wr*64 + m*16 + lg*4;
        #pragma unroll
        for (int i = 0; i < 4; ++i)
          Cf32[(size_t)(rowb + i) * N + col] = acc[m][n][i] + bv;
      }
    }
  } else {
    constexpr int LDC = 136;         // rows 272B: 16B-aligned (~2-way banks)
    ushort* Ts = smem;               // 128*136 = 17408 ushorts (aliases bufs; barrier protects)
    const bool isV = (n0 >= 2*C_);
    #pragma unroll
    for (int n = 0; n < 4; ++n){
      int cl = wc*64 + n*16 + lr;
      int col = n0 + cl;
      float bv = bias[col];
      float sc = (col < C_) ? QSCALE : 1.0f;
      if (isV){
        int rl = wr*64;
        #pragma unroll
        for (int m = 0; m < 4; ++m){
          ushort4 o;
          #pragma unroll
          for (int i = 0; i < 4; ++i) ((ushort*)&o)[i] = f2bf(acc[m][n][i] + bv);
          *(ushort4*)&Ts[cl * LDC + rl + m*16 + lg*4] = o;     // transposed: Ts[c][r]
        }
      } else {
        #pragma unroll
        for (int m = 0; m < 4; ++m){
          int rl = wr*64 + m*16 + lg*4;
          #pragma unroll
          for (int i = 0; i < 4; ++i)
            Ts[(rl + i) * LDC + cl] = f2bf((acc[m][n][i] + bv) * sc);  // Ts[r][c]
        }
      }
    }
    __syncthreads();
    const int bb = m0 >> 10, tt = m0 & 1023;
    #pragma unroll
    for (int it = 0; it < 8; ++it){
      int idx = tid + it * 256;
      int rc = idx >> 4, sg = idx & 15;
      int4 v = *(const int4*)&Ts[rc * LDC + sg * 8];
      if (isV){
        int ch = n0 - 2*C_ + rc;               // 0..767
        int hh = ch >> 6, dd = ch & 63;
        *(int4*)&Vt[((size_t)(bb * H_ + hh) * 64 + dd) * 1024 + tt + sg * 8] = v;
      } else {
        *(int4*)&qk[(size_t)(m0 + rc) * NQK_ + n0 + sg * 8] = v;
      }
    }
  }
}

// ---- fused causal flash attention: 1 wave/block + wave-private LDS staging --
// (round-9 version restored EXACTLY: single-buffered, 20.9KB LDS -> 7
// blocks/CU. Round-10 dbuf halved occupancy (36.5KB -> 4 blocks/CU) and
// DOUBLED time: this kernel is TLP-throughput-bound -- protect occupancy.)
// Per k-tile the wave stages K(64x128B) and V^T(64x128B) into PRIVATE LDS
// with 16 coalesced global_load_lds, waits its own vmcnt(0) -- NO barriers --
// then reads conflict-free XOR-swizzled ds_read_b128 frags (rule #21).
// S^T = K*Q^T; unstabilized exp2 softmax; Y^T = V^T*P^T via per-block Ps.
__global__ __launch_bounds__(64, 4) void attn_fused(const ushort* __restrict__ qk,
                        const ushort* __restrict__ Vt, ushort* __restrict__ ya){
  constexpr int LD = 72;
  __shared__ __align__(16) ushort Ks[64 * 64];   // [key][d] swizzled, 8KB
  __shared__ __align__(16) ushort Vs[64 * 64];   // [d][t]  swizzled, 8KB
  __shared__ __align__(16) ushort Ps[32 * LD];   // 4.6KB
  const int lane = threadIdx.x & 63;
  const int lr = lane & 15, lg = lane >> 4;
  const int srow = lane >> 3;              // 0..7: row within 8-row chunk
  const int sseg = (lane & 7) ^ srow;      // pre-swizzled source slot
  // bx -> (xcd, head-in-xcd, q-slice); heavy q-slices first within each XCD.
  const int bx = blockIdx.x;
  const int xcd = bx & 7, ii = bx >> 3;    // ii in 0..383
  const int hi = ii % 12, qwi = ii / 12;   // qwi in 0..31
  const int qw = 31 - qwi;                 // heavy first
  const int bh = xcd * 12 + hi;
  const int b = bh / H_, h = bh % H_;
  const ushort* Kb = qk + (size_t)b * T_ * NQK_ + C_ + h * D_;   // row stride NQK_
  const ushort* Vb = Vt + (size_t)bh * D_ * T_;                  // [d][t]

  // Q frags in registers (already scaled by QSCALE in gemm1 epilogue)
  bf16x8 qf[2][2];
  #pragma unroll
  for (int n = 0; n < 2; ++n){
    int qr = qw*32 + n*16 + lr;
    const ushort* qp = qk + ((size_t)(b * T_ + qr)) * NQK_ + h * D_;
    #pragma unroll
    for (int kk = 0; kk < 2; ++kk)
      qf[n][kk] = __builtin_bit_cast(bf16x8, *(const int4*)(qp + kk*32 + lg*8));
  }

  f32x4 yacc[4][2] = {};
  float lsum[2] = {0.f, 0.f};             // per-lane partial row-sums
  const int qwmin = qw*32;
  const int nktw = ((qwmin + 31) >> 6) + 1;
  for (int kt = 0; kt < nktw; ++kt){
    // ---- stage K,V^T tiles into private LDS (coalesced, swizzled source) ----
    #pragma unroll
    for (int c = 0; c < 8; ++c)
      gload_lds16(&Kb[(size_t)(kt*64 + c*8 + srow) * NQK_ + sseg * 8], &Ks[c * 512]);
    #pragma unroll
    for (int c = 0; c < 8; ++c)
      gload_lds16(&Vb[(size_t)(c*8 + srow) * T_ + kt*64 + sseg * 8], &Vs[c * 512]);
    asm volatile("s_waitcnt vmcnt(0)" ::: "memory");   // wave-private; no barrier

    // ---- S^T[key][q] = K * Q^T (frags from swizzled LDS) ----
    f32x4 st[4][2] = {};
    #pragma unroll
    for (int kk = 0; kk < 2; ++kk){
      bf16x8 kf[4];
      #pragma unroll
      for (int m = 0; m < 4; ++m)
        kf[m] = *(const bf16x8*)&Ks[(m*16 + lr) * 64 + ((kk*32 + lg*8) ^ ((lr & 7) << 3))];
      __builtin_amdgcn_s_setprio(1);
      #pragma unroll
      for (int m = 0; m < 4; ++m)
        #pragma unroll
        for (int n = 0; n < 2; ++n)
          st[m][n] = __builtin_amdgcn_mfma_f32_16x16x32_bf16(kf[m], qf[n][kk], st[m][n], 0, 0, 0);
      __builtin_amdgcn_s_setprio(0);
    }

    // ---- p = exp2(s) (mask only on diagonal tiles); per-lane lsum ----
    const bool needmask = (kt*64 + 63 > qwmin);
    #pragma unroll
    for (int n = 0; n < 2; ++n){
      int q = qwmin + n*16 + lr;
      float ps = 0.f;
      #pragma unroll
      for (int m = 0; m < 4; ++m){
        ushort4 pk;
        #pragma unroll
        for (int i = 0; i < 4; ++i){
          float s = st[m][n][i];
          if (needmask){
            int key = kt*64 + m*16 + lg*4 + i;
            s = (key <= q) ? s : -1e30f;
          }
          float p = __builtin_amdgcn_exp2f(s);
          ps += p;
          ((ushort*)&pk)[i] = f2bf(p);
        }
        *(ushort4*)&Ps[(n*16 + lr) * LD + m*16 + lg*4] = pk;
      }
      lsum[n] += ps;
    }

    // ---- PV: Y^T += V^T * P^T (V frags from swizzled LDS, P from Ps) ----
    #pragma unroll
    for (int kk = 0; kk < 2; ++kk){
      bf16x8 vf[4], pf[2];
      #pragma unroll
      for (int m = 0; m < 4; ++m)
        vf[m] = *(const bf16x8*)&Vs[(m*16 + lr) * 64 + ((kk*32 + lg*8) ^ ((lr & 7) << 3))];
      #pragma unroll
      for (int n = 0; n < 2; ++n)
        pf[n] = *(const bf16x8*)&Ps[(n*16 + lr) * LD + kk*32 + lg*8];
      __builtin_amdgcn_s_setprio(1);
      #pragma unroll
      for (int m = 0; m < 4; ++m)
        #pragma unroll
        for (int n = 0; n < 2; ++n)
          yacc[m][n] = __builtin_amdgcn_mfma_f32_16x16x32_bf16(vf[m], pf[n], yacc[m][n], 0, 0, 0);
      __builtin_amdgcn_s_setprio(0);
    }
  }
  // reduce lsum across the 4 lane-groups (once, after the loop)
  #pragma unroll
  for (int n = 0; n < 2; ++n){
    lsum[n] += __shfl_xor(lsum[n], 16);
    lsum[n] += __shfl_xor(lsum[n], 32);
  }
  // write ya[b, q, h*64 + d]; lane holds d = m*16 + lg*4 + i
  #pragma unroll
  for (int n = 0; n < 2; ++n){
    int q = qw*32 + n*16 + lr;
    float inv = 1.0f / lsum[n];
    #pragma unroll
    for (int m = 0; m < 4; ++m){
      ushort4 o;
      #pragma unroll
      for (int i = 0; i < 4; ++i) ((ushort*)&o)[i] = f2bf(yacc[m][n][i] * inv);
      *(ushort4*)&ya[(size_t)(b * T_ + q) * C_ + h * D_ + m*16 + lg*4] = o;
    }
  }
}

extern "C" void kernel_launch(void* const* d_in, const int* in_sizes, int n_in,
                              void* d_out, int out_size, void* d_ws, size_t ws_size,
                              hipStream_t stream){
  (void)in_sizes; (void)n_in; (void)out_size; (void)ws_size;
  const float* x  = (const float*)d_in[0];
  const float* Wa = (const float*)d_in[1];
  const float* ba = (const float*)d_in[2];
  const float* Wp = (const float*)d_in[3];
  const float* bp = (const float*)d_in[4];
  char* ws = (char*)d_ws;
  ushort* xb  = (ushort*)(ws);               // [8192][768] bf16 x (reused as ya)
  ushort* WaT = (ushort*)(ws + 12582912);    // [2304][768]
  ushort* WpT = (ushort*)(ws + 16121856);    // [768][768]
  ushort* qkb = (ushort*)(ws + 17301504);    // [8192][1536] Q(scaled)|K
  ushort* Vt  = (ushort*)(ws + 42467328);    // [96][64][1024]
  ushort* ya  = xb;                          // total 55,050,240 B

  cvt_f32_bf16<<<dim3((M_*C_)/1024), dim3(256), 0, stream>>>(x, xb, M_*C_);
  tconv<<<dim3(N3_/32, C_/32), dim3(32,8), 0, stream>>>(Wa, WaT, C_, N3_);
  tconv<<<dim3(C_/32, C_/32), dim3(32,8), 0, stream>>>(Wp, WpT, C_, C_);
  gemm_bt<0><<<dim3(N3_/128, M_/128), dim3(256), 0, stream>>>(xb, WaT, ba, nullptr, qkb, Vt, M_, N3_, C_);
  attn_fused<<<dim3(96*32), dim3(64), 0, stream>>>(qkb, Vt, ya);
  gemm_bt<1><<<dim3(C_/128, M_/128), dim3(256), 0, stream>>>(ya, WpT, bp, (float*)d_out, nullptr, nullptr, M_, C_, C_);
}